// Round 1
// 6990.749 us; speedup vs baseline: 2.1036x; 2.1036x over previous
//
#include <hip/hip_runtime.h>
#include <cfloat>

#define D_IN   768
#define T_STEPS 4
#define KDIM   3072      // T * D_IN (reduction dim of encode)
#define HDIM   32768     // D_SAE
#define BROWS  4096      // B
#define KTOP   32        // k (reference always 32; d_in[5] not read)

// ---------------------------------------------------------------------------
// bf16x3 split-GEMM on MFMA.
// pre = (Ah+Al)·(Bh+Bl)^T + b_enc  ≈ Ah·Bh + Ah·Bl + Al·Bh   (Al·Bl ~2^-16, dropped)
// A = x - b_dec split to bf16 hi/lo, B = W_enc split to bf16 hi/lo (pre-pass).
// Tile 128x128, BK=32, 4 waves (2x2), 16x16x32 bf16 MFMA, 4x4 frags/wave,
// global_load_lds width=16 staging (m97 structure), 48 MFMA : 8 loads per step.
// ---------------------------------------------------------------------------
typedef short  bf16x8 __attribute__((ext_vector_type(8)));
typedef float  f32x4  __attribute__((ext_vector_type(4)));

__device__ __forceinline__ void gload16(const void* g, void* l) {
  __builtin_amdgcn_global_load_lds(
      (const __attribute__((address_space(1))) unsigned int*)g,
      (__attribute__((address_space(3))) unsigned int*)l, 16, 0, 0);
}

__device__ __forceinline__ unsigned short f2bf(float f) {
  unsigned u = __float_as_uint(f);
  u += 0x7fffu + ((u >> 16) & 1u);            // RNE
  return (unsigned short)(u >> 16);
}
__device__ __forceinline__ float bf2f(unsigned short h) {
  return __uint_as_float((unsigned)h << 16);
}

__global__ __launch_bounds__(256) void split_wenc(
    const float* __restrict__ W, unsigned short* __restrict__ Wh,
    unsigned short* __restrict__ Wl, size_t n4) {
  size_t i = (size_t)blockIdx.x * 256 + threadIdx.x;
  const size_t stride = (size_t)gridDim.x * 256;
  for (; i < n4; i += stride) {
    float4 v = ((const float4*)W)[i];
    ushort4 h, l;
    h.x = f2bf(v.x); l.x = f2bf(v.x - bf2f(h.x));
    h.y = f2bf(v.y); l.y = f2bf(v.y - bf2f(h.y));
    h.z = f2bf(v.z); l.z = f2bf(v.z - bf2f(h.z));
    h.w = f2bf(v.w); l.w = f2bf(v.w - bf2f(h.w));
    ((ushort4*)Wh)[i] = h;
    ((ushort4*)Wl)[i] = l;
  }
}

__global__ __launch_bounds__(256) void split_x(
    const float* __restrict__ X, const float* __restrict__ b_dec,
    unsigned short* __restrict__ Ah, unsigned short* __restrict__ Al, size_t n4) {
  size_t i = (size_t)blockIdx.x * 256 + threadIdx.x;
  const size_t stride = (size_t)gridDim.x * 256;
  for (; i < n4; i += stride) {
    float4 v = ((const float4*)X)[i];
    float4 d = ((const float4*)b_dec)[i % (KDIM / 4)];
    v.x -= d.x; v.y -= d.y; v.z -= d.z; v.w -= d.w;
    ushort4 h, l;
    h.x = f2bf(v.x); l.x = f2bf(v.x - bf2f(h.x));
    h.y = f2bf(v.y); l.y = f2bf(v.y - bf2f(h.y));
    h.z = f2bf(v.z); l.z = f2bf(v.z - bf2f(h.z));
    h.w = f2bf(v.w); l.w = f2bf(v.w - bf2f(h.w));
    ((ushort4*)Ah)[i] = h;
    ((ushort4*)Al)[i] = l;
  }
}

#define BKs 32

__global__ __launch_bounds__(256) void gemm_enc_mfma(
    const unsigned short* __restrict__ Ahg, const unsigned short* __restrict__ Alg,
    const unsigned short* __restrict__ Bhg, const unsigned short* __restrict__ Blg,
    const float* __restrict__ b_enc, float* __restrict__ C) {
  // grid: (rows/128, HDIM/128) -- M fast so 32 consecutive blocks share a B-panel (L2)
  __shared__ __align__(16) short Ash[2][128][BKs];   // [hi/lo][row][k]
  __shared__ __align__(16) short Bsh[2][128][BKs];
  const int tid  = threadIdx.x;
  const int bm   = blockIdx.x * 128;
  const int bn   = blockIdx.y * 128;
  const int wid  = tid >> 6;
  const int lane = tid & 63;
  const int wr   = wid >> 1;          // wave row (0..1) -> 64 M-rows
  const int wc   = wid & 1;           // wave col (0..1) -> 64 N-cols

  f32x4 zero = {0.f, 0.f, 0.f, 0.f};
  f32x4 acc[4][4];
#pragma unroll
  for (int m = 0; m < 4; ++m)
#pragma unroll
    for (int n = 0; n < 4; ++n) acc[m][n] = zero;

  // staging: linear j = i*256 + tid covers byte j*16 of the 8KB tile
  // tile row = i*64 + (tid>>2), k-offset (shorts) = (tid&3)*8
  const int lrow = tid >> 2;
  const int lk   = (tid & 3) << 3;
  const size_t rstep = (size_t)64 * KDIM;
  const unsigned short* gAh = Ahg + (size_t)(bm + lrow) * KDIM + lk;
  const unsigned short* gAl = Alg + (size_t)(bm + lrow) * KDIM + lk;
  const unsigned short* gBh = Bhg + (size_t)(bn + lrow) * KDIM + lk;
  const unsigned short* gBl = Blg + (size_t)(bn + lrow) * KDIM + lk;
  // LDS dst: wave-uniform base + lane*16 (HW); instr i adds 4096B
  short* dAh = &Ash[0][0][0] + wid * 512;
  short* dAl = &Ash[1][0][0] + wid * 512;
  short* dBh = &Bsh[0][0][0] + wid * 512;
  short* dBl = &Bsh[1][0][0] + wid * 512;

  const int kb = (lane >> 4) << 3;          // frag k-offset: 0,8,16,24
  const int ar = wr * 64 + (lane & 15);     // A frag row base
  const int br = wc * 64 + (lane & 15);     // B frag row base

  for (int k0 = 0; k0 < KDIM; k0 += BKs) {
    gload16(gAh + k0, dAh); gload16(gAh + k0 + rstep, dAh + 2048);
    gload16(gAl + k0, dAl); gload16(gAl + k0 + rstep, dAl + 2048);
    gload16(gBh + k0, dBh); gload16(gBh + k0 + rstep, dBh + 2048);
    gload16(gBl + k0, dBl); gload16(gBl + k0 + rstep, dBl + 2048);
    __syncthreads();   // compiler drains vmcnt before barrier

    bf16x8 ah[4], al[4], bh[4], bl[4];
#pragma unroll
    for (int m = 0; m < 4; ++m) {
      ah[m] = *(const bf16x8*)&Ash[0][ar + m * 16][kb];
      al[m] = *(const bf16x8*)&Ash[1][ar + m * 16][kb];
    }
#pragma unroll
    for (int n = 0; n < 4; ++n) {
      bh[n] = *(const bf16x8*)&Bsh[0][br + n * 16][kb];
      bl[n] = *(const bf16x8*)&Bsh[1][br + n * 16][kb];
    }
#pragma unroll
    for (int m = 0; m < 4; ++m)
#pragma unroll
      for (int n = 0; n < 4; ++n) {
        acc[m][n] = __builtin_amdgcn_mfma_f32_16x16x32_bf16(ah[m], bh[n], acc[m][n], 0, 0, 0);
        acc[m][n] = __builtin_amdgcn_mfma_f32_16x16x32_bf16(ah[m], bl[n], acc[m][n], 0, 0, 0);
        acc[m][n] = __builtin_amdgcn_mfma_f32_16x16x32_bf16(al[m], bh[n], acc[m][n], 0, 0, 0);
      }
    __syncthreads();   // LDS safe to overwrite next step
  }

  // C/D layout (m89-verified): col = lane&15, row = (lane>>4)*4 + reg
  const int rbase = bm + wr * 64 + ((lane >> 4) << 2);
  const int cbase = bn + wc * 64 + (lane & 15);
  float be[4];
#pragma unroll
  for (int n = 0; n < 4; ++n) be[n] = b_enc[cbase + n * 16];
#pragma unroll
  for (int m = 0; m < 4; ++m)
#pragma unroll
    for (int r = 0; r < 4; ++r) {
      float* crow = C + (size_t)(rbase + m * 16 + r) * HDIM + cbase;
#pragma unroll
      for (int n = 0; n < 4; ++n) crow[n * 16] = acc[m][n][r] + be[n];
    }
}

// ---------------------------------------------------------------------------
// Exact top-32 per row (unchanged).
// ---------------------------------------------------------------------------
__global__ __launch_bounds__(256) void topk_select(
    const float* __restrict__ pre, float* __restrict__ vals,
    int* __restrict__ idxs, float* __restrict__ u, int row0) {
  const int tid = threadIdx.x;
  const int row = row0 + blockIdx.x;
  const float* rp = pre + (size_t)blockIdx.x * HDIM;

  unsigned long long rem[2] = {0ull, 0ull};
  float lmax = -FLT_MAX;
  int lcol = 0x7FFFFFFF;
#pragma unroll 4
  for (int j = 0; j < 128; ++j) {
    float v = rp[tid + (j << 8)];
    if (v > lmax) { lmax = v; lcol = tid + (j << 8); }
  }

  __shared__ float swv[4];
  __shared__ int swi[4];
  __shared__ float wvals[KTOP];
  __shared__ int widx[KTOP];
  const int lane = tid & 63;
  const int wv_id = tid >> 6;

  for (int it = 0; it < KTOP; ++it) {
    float v = lmax;
    int ix = lcol;
#pragma unroll
    for (int off = 32; off; off >>= 1) {
      float ov = __shfl_down(v, off);
      int oi = __shfl_down(ix, off);
      if (ov > v || (ov == v && oi < ix)) { v = ov; ix = oi; }
    }
    if (lane == 0) { swv[wv_id] = v; swi[wv_id] = ix; }
    __syncthreads();
    if (tid == 0) {
      float bv = swv[0]; int bi = swi[0];
      for (int w = 1; w < 4; ++w)
        if (swv[w] > bv || (swv[w] == bv && swi[w] < bi)) { bv = swv[w]; bi = swi[w]; }
      wvals[it] = bv; widx[it] = bi;
    }
    __syncthreads();
    const int win = widx[it];
    if ((win & 255) == tid) {
      const int j = win >> 8;
      rem[j >> 6] |= 1ull << (j & 63);
      lmax = -FLT_MAX; lcol = 0x7FFFFFFF;
      for (int j2 = 0; j2 < 128; ++j2) {
        if ((rem[j2 >> 6] >> (j2 & 63)) & 1ull) continue;
        float vv = rp[tid + (j2 << 8)];
        if (vv > lmax) { lmax = vv; lcol = tid + (j2 << 8); }
      }
    }
    __syncthreads();
  }

  if (tid < KTOP) {
    float wv = wvals[tid];
    int wi = widx[tid];
    vals[(size_t)row * KTOP + tid] = wv;
    idxs[(size_t)row * KTOP + tid] = wi;
    u[(size_t)row * HDIM + wi] = wv > 0.f ? wv : 0.f;
  }
}

// ---------------------------------------------------------------------------
// Transpose W_dec (KDIM x HDIM) -> WdT (HDIM x KDIM) (unchanged).
// ---------------------------------------------------------------------------
__global__ __launch_bounds__(256) void transpose_wdec(
    const float* __restrict__ In, float* __restrict__ Out) {
  __shared__ float t[32][33];
  const int h0 = blockIdx.x * 32;
  const int c0 = blockIdx.y * 32;
  const int tx = threadIdx.x;
  const int ty = threadIdx.y;
#pragma unroll
  for (int r = 0; r < 4; ++r) {
    const int c = c0 + ty + r * 8;
    t[ty + r * 8][tx] = In[(size_t)c * HDIM + h0 + tx];
  }
  __syncthreads();
#pragma unroll
  for (int r = 0; r < 4; ++r) {
    const int h = h0 + ty + r * 8;
    Out[(size_t)h * KDIM + c0 + tx] = t[tx][ty + r * 8];
  }
}

// ---------------------------------------------------------------------------
// Decode + loss (unchanged).
// ---------------------------------------------------------------------------
__global__ __launch_bounds__(256) void decode_rows(
    const float* __restrict__ WdT, const float* __restrict__ vals,
    const int* __restrict__ idxs, const float* __restrict__ x,
    const float* __restrict__ b_dec, float* __restrict__ xhat,
    float* __restrict__ loss) {
  const int b = blockIdx.x;
  const int tid = threadIdx.x;
  __shared__ float sv[KTOP];
  __shared__ int si[KTOP];
  if (tid < KTOP) {
    float v = vals[(size_t)b * KTOP + tid];
    sv[tid] = v > 0.f ? v : 0.f;
    si[tid] = idxs[(size_t)b * KTOP + tid];
  }
  __syncthreads();

  float acc[12];
#pragma unroll
  for (int m = 0; m < 12; ++m) acc[m] = b_dec[tid + (m << 8)];
  for (int i = 0; i < KTOP; ++i) {
    const float v = sv[i];
    const float* wr = WdT + (size_t)si[i] * KDIM;
#pragma unroll
    for (int m = 0; m < 12; ++m) acc[m] = fmaf(v, wr[tid + (m << 8)], acc[m]);
  }

  float ss = 0.f;
  const size_t base = (size_t)b * KDIM;
#pragma unroll
  for (int m = 0; m < 12; ++m) {
    const int c = tid + (m << 8);
    const float xv = x[base + c];
    const float d = acc[m] - xv;
    ss = fmaf(d, d, ss);
    xhat[base + c] = acc[m];
  }
#pragma unroll
  for (int off = 32; off; off >>= 1) ss += __shfl_down(ss, off);
  __shared__ float red[4];
  if ((tid & 63) == 0) red[tid >> 6] = ss;
  __syncthreads();
  if (tid == 0)
    atomicAdd(loss, (red[0] + red[1] + red[2] + red[3]) * (1.0f / 16384.0f));
}

// ---------------------------------------------------------------------------
extern "C" void kernel_launch(void* const* d_in, const int* in_sizes, int n_in,
                              void* d_out, int out_size, void* d_ws, size_t ws_size,
                              hipStream_t stream) {
  const float* x     = (const float*)d_in[0];
  const float* W_enc = (const float*)d_in[1];
  const float* b_enc = (const float*)d_in[2];
  const float* W_dec = (const float*)d_in[3];
  const float* b_dec = (const float*)d_in[4];

  float* out  = (float*)d_out;
  float* xhat = out + 1;
  float* u    = out + 1 + (size_t)BROWS * KDIM;

  // workspace:
  // [0 .. 402.65MB): Wh(201.3MB)+Wl(201.3MB) during encode; WdT overlays after
  // then vals, idxs, Ah, Al, pre-chunk
  char* w = (char*)d_ws;
  unsigned short* Wh = (unsigned short*)w;
  unsigned short* Wl = (unsigned short*)(w + (size_t)KDIM * HDIM * 2);
  float* WdT = (float*)w;                       // reuses Wh/Wl region post-encode
  size_t off = (size_t)KDIM * HDIM * 4;         // 402,653,184
  float* vals = (float*)(w + off); off += (size_t)BROWS * KTOP * 4;
  int*   idxs = (int*)(w + off);   off += (size_t)BROWS * KTOP * 4;
  unsigned short* Ah = (unsigned short*)(w + off); off += (size_t)BROWS * KDIM * 2;
  unsigned short* Al = (unsigned short*)(w + off); off += (size_t)BROWS * KDIM * 2;
  off = (off + 255) & ~(size_t)255;
  float* pre = (float*)(w + off);
  const size_t rem_bytes = (ws_size > off) ? ws_size - off : 0;
  int chunk = (int)(rem_bytes / ((size_t)HDIM * 4));
  chunk &= ~127;
  if (chunk > BROWS) chunk = BROWS;
  if (chunk < 128) chunk = 128;

  hipMemsetAsync(out, 0, sizeof(float), stream);
  hipMemsetAsync(u, 0, (size_t)BROWS * HDIM * sizeof(float), stream);

  split_wenc<<<2048, 256, 0, stream>>>(W_enc, Wh, Wl, (size_t)KDIM * HDIM / 4);
  split_x<<<1024, 256, 0, stream>>>(x, b_dec, Ah, Al, (size_t)BROWS * KDIM / 4);

  for (int r0 = 0; r0 < BROWS; r0 += chunk) {
    const int rows = (BROWS - r0 < chunk) ? (BROWS - r0) : chunk;
    gemm_enc_mfma<<<dim3(rows / 128, HDIM / 128), 256, 0, stream>>>(
        Ah + (size_t)r0 * KDIM, Al + (size_t)r0 * KDIM, Wh, Wl, b_enc, pre);
    topk_select<<<rows, 256, 0, stream>>>(pre, vals, idxs, u, r0);
  }

  // WdT overlays Wh/Wl -> transpose must run after the encode loop
  transpose_wdec<<<dim3(HDIM / 32, KDIM / 32), dim3(32, 8), 0, stream>>>(W_dec, WdT);
  decode_rows<<<BROWS, 256, 0, stream>>>(WdT, vals, idxs, x, b_dec, xhat, out);
}